// Round 6
// baseline (220.437 us; speedup 1.0000x reference)
//
#include <hip/hip_runtime.h>
#include <stdint.h>

// DeformationGraph R6: R5 structure, spill-free register budget.
//  - R5's __launch_bounds__(256,8) forced VGPR=32 -> compiler spilled m[20]
//    and the merge arr[32] to scratch: WRITE_SIZE 3MB->74MB, FETCH +25MB.
//    R6 uses (256,4) (R3-proven spill-free; VGPR~64) - only change.
//  - Wave layout: block = 32 points; wave wv: pg=wv>>1 -> 16 points,
//    half=wv&1 -> nodes [half*2048,(half+1)*2048). 2048 blocks.
//  - Scan: per 16x16 tile, mfma_f32_16x16x32_bf16 with 3-way bf16 split
//    (fp32-exact dot); branchless push into per-lane LDS stack gated by thr.
//  - thr SHARED across the 4 g-lanes of a point after each drain (min of
//    per-subset 20th-smallest >= union 20th -> exact set preserved).
//  - Drains at chunk ends {4,8,16,32,64,128} tiles + __any(cnt>=15) guard.
//  - In-wave 4-list bitonic merge (shfl_xor), cross-wave min-merge via LDS,
//    exact fp32 reference-formula recompute for the final 20 (far-flag razor
//    edge), distributed blend, half==0 writes.

#define NPTS   65536
#define NNODES 4096
#define KSEL   20
#define CAP    19
#define BT     256
#define PPB    32
#define AFRAG_BYTES  (NNODES * 64)
#define WS_NEEDED    (AFRAG_BYTES + NNODES * 4)

typedef __attribute__((ext_vector_type(8))) short short8;
typedef __attribute__((ext_vector_type(4))) float f32x4;

__device__ __forceinline__ uint32_t umin32(uint32_t a, uint32_t b) { return a < b ? a : b; }
__device__ __forceinline__ uint32_t umax32(uint32_t a, uint32_t b) { return a > b ? a : b; }
__device__ __forceinline__ void cmpswap(uint32_t& a, uint32_t& b) {
  const uint32_t lo = umin32(a, b), hi = umax32(a, b); a = lo; b = hi;
}
__device__ __forceinline__ void insert20(uint32_t m[KSEL], uint32_t x) {
#pragma unroll
  for (int k = KSEL - 1; k >= 1; --k)
    m[k] = umin32(m[k], umax32(m[k - 1], x));
  m[0] = umin32(m[0], x);
}
__device__ __forceinline__ float thr_from(uint32_t m19) {
  return __uint_as_float(umin32((m19 >> 12) << 11, 0x7F7FFFFFu));
}
__device__ __forceinline__ unsigned short f2bf(float x) {   // RNE fp32->bf16
  uint32_t u = __float_as_uint(x);
  return (unsigned short)((u + 0x7FFFu + ((u >> 16) & 1u)) >> 16);
}
__device__ __forceinline__ float bf2f(unsigned short h) {
  return __uint_as_float(((uint32_t)h) << 16);
}

// prep: per-node A-fragment (32 bf16 = [h0,h1,h2,m0,m1,m2,l0,l1,l2]x3 + pad)
// + fp32 |v|^2 table
__global__ void dg_prep(const float* __restrict__ vd,
                        unsigned short* __restrict__ aF, float* __restrict__ sv) {
  const int j = blockIdx.x * 256 + threadIdx.x;
  const float v0 = vd[j * 3 + 0], v1 = vd[j * 3 + 1], v2 = vd[j * 3 + 2];
  unsigned short h[3], mm[3], ll[3];
  const float vc[3] = {v0, v1, v2};
#pragma unroll
  for (int c = 0; c < 3; ++c) {
    h[c] = f2bf(vc[c]);
    const float r1 = vc[c] - bf2f(h[c]);
    mm[c] = f2bf(r1);
    const float r2 = r1 - bf2f(mm[c]);
    ll[c] = f2bf(r2);
  }
  unsigned short* o = aF + j * 32;
#pragma unroll
  for (int rep = 0; rep < 3; ++rep) {
    o[rep * 9 + 0] = h[0];  o[rep * 9 + 1] = h[1];  o[rep * 9 + 2] = h[2];
    o[rep * 9 + 3] = mm[0]; o[rep * 9 + 4] = mm[1]; o[rep * 9 + 5] = mm[2];
    o[rep * 9 + 6] = ll[0]; o[rep * 9 + 7] = ll[1]; o[rep * 9 + 8] = ll[2];
  }
#pragma unroll
  for (int k = 27; k < 32; ++k) o[k] = 0;
  sv[j] = v0 * v0 + v1 * v1 + v2 * v2;
}

__global__ __launch_bounds__(BT, 4) void dg_mfma(
    const float* __restrict__ inp, const float* __restrict__ vd,
    const float* __restrict__ Rm, const float* __restrict__ gv,
    const float* __restrict__ tv, const short8* __restrict__ aF,
    const float4* __restrict__ sv4, float* __restrict__ out)
{
  __shared__ uint32_t st[CAP * BT];        // 19456 B
  const int tid  = threadIdx.x;
  const int pl   = tid & 15;               // point col
  const int g    = (tid >> 4) & 3;         // node row group
  const int wv   = tid >> 6;
  const int half = wv & 1;                 // node half
  const int pg   = wv >> 1;                // point group
  const int gi   = blockIdx.x * PPB + pg * 16 + pl;

  const float p0 = inp[gi * 35 + 0];
  const float p1 = inp[gi * 35 + 1];
  const float p2 = inp[gi * 35 + 2];
  const float sp = p0 * p0 + p1 * p1 + p2 * p2;

  // B fragment: 3-way split of (-2p); slot k=9s+3t+c holds -2 p_s[c].
  unsigned short qh[3], qm[3], ql[3];
  {
    const float qc[3] = {-2.0f * p0, -2.0f * p1, -2.0f * p2};
#pragma unroll
    for (int c = 0; c < 3; ++c) {
      qh[c] = f2bf(qc[c]);
      const float r1 = qc[c] - bf2f(qh[c]);
      qm[c] = f2bf(r1);
      const float r2 = r1 - bf2f(qm[c]);
      ql[c] = f2bf(r2);
    }
  }
  short8 b;
  if (g == 0) {
    b[0]=qh[0]; b[1]=qh[1]; b[2]=qh[2]; b[3]=qh[0]; b[4]=qh[1]; b[5]=qh[2]; b[6]=qh[0]; b[7]=qh[1];
  } else if (g == 1) {
    b[0]=qh[2]; b[1]=qm[0]; b[2]=qm[1]; b[3]=qm[2]; b[4]=qm[0]; b[5]=qm[1]; b[6]=qm[2]; b[7]=qm[0];
  } else if (g == 2) {
    b[0]=qm[1]; b[1]=qm[2]; b[2]=ql[0]; b[3]=ql[1]; b[4]=ql[2]; b[5]=ql[0]; b[6]=ql[1]; b[7]=ql[2];
  } else {
    b[0]=ql[0]; b[1]=ql[1]; b[2]=ql[2]; b[3]=0; b[4]=0; b[5]=0; b[6]=0; b[7]=0;
  }

  uint32_t m[KSEL];
#pragma unroll
  for (int k = 0; k < KSEL; ++k) m[k] = 0xFFFFFFFFu;
  uint32_t cnt = 0;
  float thr = __uint_as_float(0x7F7FFFFFu);

  auto drain = [&]() {
    for (uint32_t u = 0; u < cnt; ++u) {
      const uint32_t x = st[u * BT + tid];
      if (x < m[KSEL - 1]) insert20(m, x);
    }
    cnt = 0;
    // share the threshold across the 4 g-lanes of this point (safe: min of
    // per-subset 20th-smallest >= 20th-smallest of the union)
    uint32_t k19 = m[KSEL - 1];
    k19 = umin32(k19, (uint32_t)__shfl_xor((int)k19, 16));
    k19 = umin32(k19, (uint32_t)__shfl_xor((int)k19, 32));
    thr = thr_from(k19);
  };

  const int Tb = half * 128;               // tile base (16 nodes per tile)
  constexpr int CH[6] = {4, 8, 16, 32, 64, 128};
  int t = 0;
#pragma unroll
  for (int c = 0; c < 6; ++c) {
    const int t1 = CH[c];
#pragma unroll 1
    for (; t < t1; ++t) {
      const int T  = Tb + t;
      const int nb = T * 16 + g * 4;
      const short8 a  = aF[(T * 16 + pl) * 4 + g];
      const float4 s4 = sv4[T * 4 + g];
      f32x4 acc;
      acc[0] = sp + s4.x; acc[1] = sp + s4.y; acc[2] = sp + s4.z; acc[3] = sp + s4.w;
      acc = __builtin_amdgcn_mfma_f32_16x16x32_bf16(a, b, acc, 0, 0, 0);
#pragma unroll
      for (int i = 0; i < 4; ++i) {
        const float d = acc[i];
        // branchless push: pack+write always, advance cnt on hit
        const uint32_t key =
            ((__float_as_uint(fmaxf(d, 0.0f)) & 0xFFFFF800u) << 1)
            + (uint32_t)(nb + i);
        st[cnt * BT + tid] = key;
        cnt += (uint32_t)(d < thr);
      }
      if (__any((int)(cnt >= CAP - 4))) drain();   // wave-uniform guard
    }
    drain();                                        // chunk-boundary drain
  }

  // ---- in-wave merge of the 4 row-group lists -> sorted top-20 of half ----
  uint32_t arr[32];
#pragma unroll
  for (int k = 0; k < KSEL; ++k) arr[k] = m[k];
#pragma unroll
  for (int k = KSEL; k < 32; ++k) arr[k] = 0xFFFFFFFFu;
#pragma unroll
  for (int mask = 32; mask >= 16; mask >>= 1) {
#pragma unroll
    for (int k = 0; k < 16; ++k) {
      const uint32_t sa = (uint32_t)__shfl_xor((int)arr[k],      mask);
      const uint32_t sb = (uint32_t)__shfl_xor((int)arr[31 - k], mask);
      arr[k]      = umin32(arr[k],      sb);
      arr[31 - k] = umin32(arr[31 - k], sa);
    }
#pragma unroll
    for (int dd = 16; dd >= 1; dd >>= 1)
#pragma unroll
      for (int k = 0; k < 32; ++k)
        if ((k & dd) == 0) cmpswap(arr[k], arr[k | dd]);
  }

  // ---- cross-wave merge: half 1 publishes, half 0 min-merges ----
  __syncthreads();                          // stacks dead; reuse st
  if (half == 1 && g == 0) {
    uint32_t* mb = st + (pg * 16 + pl) * KSEL;
#pragma unroll
    for (int k = 0; k < KSEL; ++k) mb[k] = arr[k];
  }
  __syncthreads();
  if (half == 1) return;

  uint32_t sset[KSEL];
  {
    const uint32_t* mb = st + (pg * 16 + pl) * KSEL;
#pragma unroll
    for (int k = 0; k < KSEL; ++k)
      sset[k] = umin32(arr[k], mb[KSEL - 1 - k]);   // 20-smallest (unsorted)
  }

  // ---- distributed exact recompute (lane g handles k = g,4+g,...) ----
  int   id5[5];
  float d5[5];
  float dmn = 1e30f, dmx = -1e30f;
#pragma unroll
  for (int s = 0; s < 5; ++s) {
    const int idk = (int)(sset[4 * s + g] & 0xFFFu);
    id5[s] = idk;
    const float v0 = vd[idk * 3 + 0];
    const float v1 = vd[idk * 3 + 1];
    const float v2 = vd[idk * 3 + 2];
    const float sv = v0 * v0 + v1 * v1 + v2 * v2;
    const float dt = p0 * v0 + p1 * v1 + p2 * v2;
    const float ddx = (sp + sv) - 2.0f * dt;        // reference formula
    d5[s] = ddx;
    dmn = fminf(dmn, ddx);
    dmx = fmaxf(dmx, ddx);
  }
#pragma unroll
  for (int r = 16; r <= 32; r <<= 1) {
    dmx = fmaxf(dmx, __shfl_xor(dmx, r));
    dmn = fminf(dmn, __shfl_xor(dmn, r));
  }

  const float invmax = 1.0f / dmx;
  float wsum = 0.0f, pb0 = 0.0f, pb1 = 0.0f, pb2 = 0.0f;
  float rb[9];
#pragma unroll
  for (int a2 = 0; a2 < 9; ++a2) rb[a2] = 0.0f;

#pragma unroll
  for (int s = 0; s < 5; ++s) {
    const int idk = id5[s];
    const float u = 1.0f - d5[s] * invmax;
    const float w = u * u;
    wsum += w;
    const float* Rp = Rm + idk * 9;
    const float r00 = Rp[0], r01 = Rp[1], r02 = Rp[2];
    const float r10 = Rp[3], r11 = Rp[4], r12 = Rp[5];
    const float r20 = Rp[6], r21 = Rp[7], r22 = Rp[8];
    const float g0 = gv[idk * 3 + 0];
    const float g1 = gv[idk * 3 + 1];
    const float g2 = gv[idk * 3 + 2];
    const float t0 = tv[idk * 3 + 0];
    const float t1 = tv[idk * 3 + 1];
    const float t2 = tv[idk * 3 + 2];
    const float x0 = p0 - g0 - t0;
    const float x1 = p1 - g1 - t1;
    const float x2 = p2 - g2 - t2;
    pb0 += w * (r00 * x0 + r10 * x1 + r20 * x2 + g0);
    pb1 += w * (r01 * x0 + r11 * x1 + r21 * x2 + g1);
    pb2 += w * (r02 * x0 + r12 * x1 + r22 * x2 + g2);
    rb[0] += w * r00; rb[1] += w * r10; rb[2] += w * r20;
    rb[3] += w * r01; rb[4] += w * r11; rb[5] += w * r21;
    rb[6] += w * r02; rb[7] += w * r12; rb[8] += w * r22;
  }

#pragma unroll
  for (int r = 16; r <= 32; r <<= 1) {
    wsum += __shfl_xor(wsum, r);
    pb0  += __shfl_xor(pb0, r);
    pb1  += __shfl_xor(pb1, r);
    pb2  += __shfl_xor(pb2, r);
#pragma unroll
    for (int a2 = 0; a2 < 9; ++a2) rb[a2] += __shfl_xor(rb[a2], r);
  }

  if (g == 0) {
    const float inw = 1.0f / wsum;
    float o0 = pb0 * inw;
    if (dmn > 0.00021f) o0 = 1000000000.0f;
    float* po = out + (size_t)gi * 3;
    po[0] = o0; po[1] = pb1 * inw; po[2] = pb2 * inw;
    float* ro = out + (size_t)NPTS * 3 + (size_t)gi * 9;
#pragma unroll
    for (int a2 = 0; a2 < 9; ++a2) ro[a2] = rb[a2] * inw;
  }
}

// ---- fallback: R2 scalar kernel (proven), used only if ws too small ----
__global__ __launch_bounds__(BT, 4) void dg_fb(
    const float* __restrict__ inp, const float* __restrict__ vd,
    const float* __restrict__ Rm, const float* __restrict__ gv,
    const float* __restrict__ tv, float* __restrict__ out)
{
  __shared__ uint32_t st[33 * BT];
  const int tid = threadIdx.x;
  const int q   = (tid >> 4) & 3;
  const int pl  = tid & 15;
  const int wv  = tid >> 6;
  const int gi  = blockIdx.x * 64 + wv * 16 + pl;
  const float p0 = inp[gi * 35 + 0];
  const float p1 = inp[gi * 35 + 1];
  const float p2 = inp[gi * 35 + 2];
  const float sp = p0 * p0 + p1 * p1 + p2 * p2;
  uint32_t m[KSEL];
#pragma unroll
  for (int k = 0; k < KSEL; ++k) m[k] = 0xFFFFFFFFu;
  int cnt = 0;
  float thr = __uint_as_float(0x7F7FFFFFu);
  const int jbase = q * (NNODES / 4);
  int lo = 0;
#pragma unroll
  for (int c = 0; c < 6; ++c) {
    const int hi = 32 << c;
    for (int i = lo; i < hi; ++i) {
      const int j = jbase + i;
      const float v0 = vd[j * 3 + 0], v1 = vd[j * 3 + 1], v2 = vd[j * 3 + 2];
      const float sv = v0 * v0 + v1 * v1 + v2 * v2;
      const float dt = p0 * v0 + p1 * v1 + p2 * v2;
      float d2 = fmaxf((sp + sv) - 2.0f * dt, 0.0f);
      if (d2 < thr) {
        st[cnt * BT + tid] = ((__float_as_uint(d2) & 0xFFFFF800u) << 1) | (uint32_t)j;
        if (++cnt == 33) {
          for (int u = 0; u < cnt; ++u) {
            const uint32_t x = st[u * BT + tid];
            if (x < m[KSEL - 1]) insert20(m, x);
          }
          cnt = 0; thr = thr_from(m[KSEL - 1]);
        }
      }
    }
    for (int u = 0; u < cnt; ++u) {
      const uint32_t x = st[u * BT + tid];
      if (x < m[KSEL - 1]) insert20(m, x);
    }
    cnt = 0; thr = thr_from(m[KSEL - 1]); lo = hi;
  }
  uint32_t arr[32];
#pragma unroll
  for (int k = 0; k < KSEL; ++k) arr[k] = m[k];
#pragma unroll
  for (int k = KSEL; k < 32; ++k) arr[k] = 0xFFFFFFFFu;
#pragma unroll
  for (int mask = 32; mask >= 16; mask >>= 1) {
#pragma unroll
    for (int k = 0; k < 16; ++k) {
      const uint32_t sa = (uint32_t)__shfl_xor((int)arr[k],      mask);
      const uint32_t sb = (uint32_t)__shfl_xor((int)arr[31 - k], mask);
      arr[k]      = umin32(arr[k],      sb);
      arr[31 - k] = umin32(arr[31 - k], sa);
    }
#pragma unroll
    for (int dd = 16; dd >= 1; dd >>= 1)
#pragma unroll
      for (int k = 0; k < 32; ++k)
        if ((k & dd) == 0) cmpswap(arr[k], arr[k | dd]);
  }
  int id5[5]; float d5[5];
  float dmn = 1e30f, dmx = -1e30f;
#pragma unroll
  for (int s = 0; s < 5; ++s) {
    const int idk = (int)(arr[4 * s + q] & 0xFFFu);
    id5[s] = idk;
    const float v0 = vd[idk * 3 + 0], v1 = vd[idk * 3 + 1], v2 = vd[idk * 3 + 2];
    const float sv = v0 * v0 + v1 * v1 + v2 * v2;
    const float dt = p0 * v0 + p1 * v1 + p2 * v2;
    const float ddx = (sp + sv) - 2.0f * dt;
    d5[s] = ddx; dmn = fminf(dmn, ddx); dmx = fmaxf(dmx, ddx);
  }
#pragma unroll
  for (int r = 16; r <= 32; r <<= 1) {
    dmx = fmaxf(dmx, __shfl_xor(dmx, r));
    dmn = fminf(dmn, __shfl_xor(dmn, r));
  }
  const float invmax = 1.0f / dmx;
  float wsum = 0.0f, pb0 = 0.0f, pb1 = 0.0f, pb2 = 0.0f;
  float rb[9];
#pragma unroll
  for (int a2 = 0; a2 < 9; ++a2) rb[a2] = 0.0f;
#pragma unroll
  for (int s = 0; s < 5; ++s) {
    const int idk = id5[s];
    const float u = 1.0f - d5[s] * invmax;
    const float w = u * u;
    wsum += w;
    const float* Rp = Rm + idk * 9;
    const float r00 = Rp[0], r01 = Rp[1], r02 = Rp[2];
    const float r10 = Rp[3], r11 = Rp[4], r12 = Rp[5];
    const float r20 = Rp[6], r21 = Rp[7], r22 = Rp[8];
    const float g0 = gv[idk * 3 + 0], g1 = gv[idk * 3 + 1], g2 = gv[idk * 3 + 2];
    const float t0 = tv[idk * 3 + 0], t1 = tv[idk * 3 + 1], t2 = tv[idk * 3 + 2];
    const float x0 = p0 - g0 - t0, x1 = p1 - g1 - t1, x2 = p2 - g2 - t2;
    pb0 += w * (r00 * x0 + r10 * x1 + r20 * x2 + g0);
    pb1 += w * (r01 * x0 + r11 * x1 + r21 * x2 + g1);
    pb2 += w * (r02 * x0 + r12 * x1 + r22 * x2 + g2);
    rb[0] += w * r00; rb[1] += w * r10; rb[2] += w * r20;
    rb[3] += w * r01; rb[4] += w * r11; rb[5] += w * r21;
    rb[6] += w * r02; rb[7] += w * r12; rb[8] += w * r22;
  }
#pragma unroll
  for (int r = 16; r <= 32; r <<= 1) {
    wsum += __shfl_xor(wsum, r);
    pb0 += __shfl_xor(pb0, r);
    pb1 += __shfl_xor(pb1, r);
    pb2 += __shfl_xor(pb2, r);
#pragma unroll
    for (int a2 = 0; a2 < 9; ++a2) rb[a2] += __shfl_xor(rb[a2], r);
  }
  if (q == 0) {
    const float inw = 1.0f / wsum;
    float o0 = pb0 * inw;
    if (dmn > 0.00021f) o0 = 1000000000.0f;
    float* po = out + (size_t)gi * 3;
    po[0] = o0; po[1] = pb1 * inw; po[2] = pb2 * inw;
    float* ro = out + (size_t)NPTS * 3 + (size_t)gi * 9;
#pragma unroll
    for (int a2 = 0; a2 < 9; ++a2) ro[a2] = rb[a2] * inw;
  }
}

extern "C" void kernel_launch(void* const* d_in, const int* in_sizes, int n_in,
                              void* d_out, int out_size, void* d_ws, size_t ws_size,
                              hipStream_t stream) {
  const float* inp = (const float*)d_in[0];
  const float* vd  = (const float*)d_in[1];
  const float* Rm  = (const float*)d_in[2];
  const float* gv  = (const float*)d_in[3];
  const float* tv  = (const float*)d_in[4];
  float* out = (float*)d_out;

  if (ws_size >= (size_t)WS_NEEDED) {
    unsigned short* aF = (unsigned short*)d_ws;
    float* svt = (float*)((char*)d_ws + AFRAG_BYTES);
    dg_prep<<<NNODES / 256, 256, 0, stream>>>(vd, aF, svt);
    dg_mfma<<<NPTS / PPB, BT, 0, stream>>>(inp, vd, Rm, gv, tv,
                                           (const short8*)aF,
                                           (const float4*)svt, out);
  } else {
    dg_fb<<<NPTS / 64, BT, 0, stream>>>(inp, vd, Rm, gv, tv, out);
  }
}

// Round 7
// 163.483 us; speedup vs baseline: 1.3484x; 1.3484x over previous
//
#include <hip/hip_runtime.h>
#include <stdint.h>

// DeformationGraph R7: 32x32 MFMA distances (16 cand/lane/tile), exact 3-way
// bf16 split across TWO chained mfma_f32_32x32x16_bf16 (16+11 of 32 k-slots).
//  - Wave = 32 points x 2048 nodes (64 tiles of 32). Block = 4 waves =
//    64 points x 2 node-halves. Grid 1024 = exactly 4 blocks/CU.
//  - C/D layout (m74/m101): col=lane&31 -> point, row=(reg&3)+8*(reg>>2)+
//    4*(lane>>5) -> node. Lane pair (l, l^32) covers a point.
//  - A (nodes) tables precomputed (64B/node: A1h0|A1h1|A2h0|A2h1); B (points)
//    built in-register per lane half. Same slot convention both sides -> HW
//    k-permutation cancels (validated by R3-R6 passing exactly).
//  - Selection: packed u32 keys (d2bits>>11<<12 | idx), per-lane LDS stack,
//    guard-only drains (trigger cnt>=16, CAP=32 provably overflow-free),
//    insert20 min/max chain, thr shared across the lane pair (shfl_xor 32).
//  - Epilogue: pair bitonic merge -> sorted top-20/half; cross-wave min-merge
//    via LDS; exact fp32 reference-formula recompute (far-flag razor edge);
//    blend split 10/lane; h==0 writes.

#define NPTS   65536
#define NNODES 4096
#define KSEL   20
#define CAP    32
#define BT     256
#define AFRAG_BYTES  (NNODES * 64)
#define WS_NEEDED    (AFRAG_BYTES + NNODES * 4)

typedef __attribute__((ext_vector_type(8)))  short short8;
typedef __attribute__((ext_vector_type(16))) float f32x16;

__device__ __forceinline__ uint32_t umin32(uint32_t a, uint32_t b) { return a < b ? a : b; }
__device__ __forceinline__ uint32_t umax32(uint32_t a, uint32_t b) { return a > b ? a : b; }
__device__ __forceinline__ void cmpswap(uint32_t& a, uint32_t& b) {
  const uint32_t lo = umin32(a, b), hi = umax32(a, b); a = lo; b = hi;
}
__device__ __forceinline__ void insert20(uint32_t m[KSEL], uint32_t x) {
#pragma unroll
  for (int k = KSEL - 1; k >= 1; --k)
    m[k] = umin32(m[k], umax32(m[k - 1], x));
  m[0] = umin32(m[0], x);
}
__device__ __forceinline__ float thr_from(uint32_t m19) {
  return __uint_as_float(umin32((m19 >> 12) << 11, 0x7F7FFFFFu));
}
__device__ __forceinline__ unsigned short f2bf(float x) {   // RNE fp32->bf16
  uint32_t u = __float_as_uint(x);
  return (unsigned short)((u + 0x7FFFu + ((u >> 16) & 1u)) >> 16);
}
__device__ __forceinline__ float bf2f(unsigned short h) {
  return __uint_as_float(((uint32_t)h) << 16);
}

// prep: per-node A tables + permuted |v|^2 table.
// A1 = [vH0,vH1,vH2,vM0,vM1,vM2,vL0,vL1 | vL2,vH0,vH1,vH2,vM0,vM1,vM2,vL0]
// A2 = [vL1,vL2,vH0,vH1,vH2,vM0,vM1,vM2 | vL0,vL1,vL2,0,0,0,0,0]
// layout per node (64B): A1h0(16B) A1h1 A2h0 A2h1.
// svP[t*32 + h*16 + i] = |v|^2 of node t*32 + (i&3)+8*(i>>2)+4h.
__global__ void dg_prep(const float* __restrict__ vd,
                        unsigned short* __restrict__ aF, float* __restrict__ svP) {
  const int j = blockIdx.x * 256 + threadIdx.x;
  const float v0 = vd[j * 3 + 0], v1 = vd[j * 3 + 1], v2 = vd[j * 3 + 2];
  unsigned short H[3], M[3], L[3];
  const float vc[3] = {v0, v1, v2};
#pragma unroll
  for (int c = 0; c < 3; ++c) {
    H[c] = f2bf(vc[c]);
    const float r1 = vc[c] - bf2f(H[c]);
    M[c] = f2bf(r1);
    const float r2 = r1 - bf2f(M[c]);
    L[c] = f2bf(r2);
  }
  unsigned short* o = aF + j * 32;
  // A1 (slots 0..15)
  o[0]=H[0]; o[1]=H[1]; o[2]=H[2]; o[3]=M[0]; o[4]=M[1]; o[5]=M[2];
  o[6]=L[0]; o[7]=L[1]; o[8]=L[2]; o[9]=H[0]; o[10]=H[1]; o[11]=H[2];
  o[12]=M[0]; o[13]=M[1]; o[14]=M[2]; o[15]=L[0];
  // A2 (slots 0..15)
  o[16]=L[1]; o[17]=L[2]; o[18]=H[0]; o[19]=H[1]; o[20]=H[2];
  o[21]=M[0]; o[22]=M[1]; o[23]=M[2]; o[24]=L[0]; o[25]=L[1]; o[26]=L[2];
  o[27]=0; o[28]=0; o[29]=0; o[30]=0; o[31]=0;
  // svP permutation: row -> (h, i)
  const int row = j & 31, t = j >> 5;
  const int h = (row >> 2) & 1;
  const int i = (row & 3) + 4 * (row >> 3);
  svP[t * 32 + h * 16 + i] = v0 * v0 + v1 * v1 + v2 * v2;
}

__global__ __launch_bounds__(BT, 4) void dg_mfma(
    const float* __restrict__ inp, const float* __restrict__ vd,
    const float* __restrict__ Rm, const float* __restrict__ gv,
    const float* __restrict__ tv, const short8* __restrict__ aF,
    const float4* __restrict__ svP, float* __restrict__ out)
{
  __shared__ uint32_t st[CAP * BT];        // 32 KB per-lane stacks
  const int tid  = threadIdx.x;
  const int lane = tid & 63;
  const int col  = lane & 31;              // point within wave's 32
  const int h    = lane >> 5;              // k-half / row-group bit
  const int wv   = tid >> 6;
  const int half = wv & 1;                 // node half (2048 nodes)
  const int pg   = wv >> 1;                // point group (32 points)
  const int P    = pg * 32 + col;          // block-local point id (0..63)
  const int gi   = blockIdx.x * 64 + P;

  const float p0 = inp[gi * 35 + 0];
  const float p1 = inp[gi * 35 + 1];
  const float p2 = inp[gi * 35 + 2];
  const float sp = p0 * p0 + p1 * p1 + p2 * p2;

  // 3-way split of (-2p) -> B fragments for this lane's k-half.
  unsigned short qH[3], qM[3], qL[3];
  {
    const float qc[3] = {-2.0f * p0, -2.0f * p1, -2.0f * p2};
#pragma unroll
    for (int c = 0; c < 3; ++c) {
      qH[c] = f2bf(qc[c]);
      const float r1 = qc[c] - bf2f(qH[c]);
      qM[c] = f2bf(r1);
      const float r2 = r1 - bf2f(qM[c]);
      qL[c] = f2bf(r2);
    }
  }
  short8 b1, b2;
  if (h == 0) {
    b1[0]=qH[0]; b1[1]=qH[1]; b1[2]=qH[2]; b1[3]=qH[0];
    b1[4]=qH[1]; b1[5]=qH[2]; b1[6]=qH[0]; b1[7]=qH[1];
    b2[0]=qM[1]; b2[1]=qM[2]; b2[2]=qL[0]; b2[3]=qL[1];
    b2[4]=qL[2]; b2[5]=qL[0]; b2[6]=qL[1]; b2[7]=qL[2];
  } else {
    b1[0]=qH[2]; b1[1]=qM[0]; b1[2]=qM[1]; b1[3]=qM[2];
    b1[4]=qM[0]; b1[5]=qM[1]; b1[6]=qM[2]; b1[7]=qM[0];
    b2[0]=qL[0]; b2[1]=qL[1]; b2[2]=qL[2]; b2[3]=0;
    b2[4]=0; b2[5]=0; b2[6]=0; b2[7]=0;
  }

  uint32_t m[KSEL];
#pragma unroll
  for (int k = 0; k < KSEL; ++k) m[k] = 0xFFFFFFFFu;
  uint32_t cnt = 0;
  float thr = __uint_as_float(0x7F7FFFFFu);

  auto drain = [&]() {
    for (uint32_t u = 0; u < cnt; ++u) {
      const uint32_t x = st[u * BT + tid];
      if (x < m[KSEL - 1]) insert20(m, x);
    }
    cnt = 0;
    uint32_t k19 = m[KSEL - 1];
    k19 = umin32(k19, (uint32_t)__shfl_xor((int)k19, 32));  // pair share
    thr = thr_from(k19);
  };

  const int T0 = half * 64;                 // 64 tiles of 32 nodes per half
  // per-lane pointers (advance by constant strides per tile)
  const short8* ap = aF + ((size_t)(T0 * 32 + col) * 64 + (size_t)h * 16) / 16;
  const float4* sv = svP + ((size_t)T0 * 32 + (size_t)h * 16) / 4;
  uint32_t nb = (uint32_t)(T0 * 32 + 4 * h);  // node base for this lane's rows

#pragma unroll 1
  for (int t = 0; t < 64; ++t) {
    const short8 a1 = ap[0];
    const short8 a2 = ap[2];                // +32B
    const float4 s0 = sv[0], s1 = sv[1], s2 = sv[2], s3 = sv[3];
    f32x16 acc;
    acc[0]=sp+s0.x;  acc[1]=sp+s0.y;  acc[2]=sp+s0.z;  acc[3]=sp+s0.w;
    acc[4]=sp+s1.x;  acc[5]=sp+s1.y;  acc[6]=sp+s1.z;  acc[7]=sp+s1.w;
    acc[8]=sp+s2.x;  acc[9]=sp+s2.y;  acc[10]=sp+s2.z; acc[11]=sp+s2.w;
    acc[12]=sp+s3.x; acc[13]=sp+s3.y; acc[14]=sp+s3.z; acc[15]=sp+s3.w;
    acc = __builtin_amdgcn_mfma_f32_32x32x16_bf16(a1, b1, acc, 0, 0, 0);
    acc = __builtin_amdgcn_mfma_f32_32x32x16_bf16(a2, b2, acc, 0, 0, 0);
#pragma unroll
    for (int i = 0; i < 16; ++i) {
      const float d = acc[i];
      const uint32_t key =
          ((__float_as_uint(fmaxf(d, 0.0f)) & 0xFFFFF800u) << 1)
          + (nb + (uint32_t)((i & 3) + 8 * (i >> 2)));
      st[cnt * BT + tid] = key;
      cnt += (uint32_t)(d < thr);
    }
    if (__any((int)(cnt >= 16))) drain();
    ap += 4 * 32;                           // 32 nodes * 64B / 16B
    sv += 8;                                // 128B / 16B
    nb += 32;
  }
  drain();                                  // final

  // ---- pair merge (lane l <-> l^32): sorted top-20 of this half ----
  uint32_t arr[32];
#pragma unroll
  for (int k = 0; k < KSEL; ++k) arr[k] = m[k];
#pragma unroll
  for (int k = KSEL; k < 32; ++k) arr[k] = 0xFFFFFFFFu;
#pragma unroll
  for (int k = 0; k < 16; ++k) {
    const uint32_t sa = (uint32_t)__shfl_xor((int)arr[k],      32);
    const uint32_t sb = (uint32_t)__shfl_xor((int)arr[31 - k], 32);
    arr[k]      = umin32(arr[k],      sb);
    arr[31 - k] = umin32(arr[31 - k], sa);
  }
#pragma unroll
  for (int dd = 16; dd >= 1; dd >>= 1)
#pragma unroll
    for (int k = 0; k < 32; ++k)
      if ((k & dd) == 0) cmpswap(arr[k], arr[k | dd]);

  // ---- cross-wave merge over node halves ----
  __syncthreads();                          // stacks dead; reuse st
  if (half == 1 && h == 0) {
    uint32_t* mb = st + P * KSEL;
#pragma unroll
    for (int k = 0; k < KSEL; ++k) mb[k] = arr[k];
  }
  __syncthreads();
  if (half == 1) return;

  uint32_t sset[KSEL];
  {
    const uint32_t* mb = st + P * KSEL;
#pragma unroll
    for (int k = 0; k < KSEL; ++k)
      sset[k] = umin32(arr[k], mb[KSEL - 1 - k]);   // top-20 SET (unsorted)
  }

  // ---- distributed exact recompute: lane h handles k = 2s+h, s=0..9 ----
  int   id10[10];
  float d10[10];
  float dmn = 1e30f, dmx = -1e30f;
#pragma unroll
  for (int s = 0; s < 10; ++s) {
    const int idk = (int)(sset[2 * s + h] & 0xFFFu);
    id10[s] = idk;
    const float v0 = vd[idk * 3 + 0];
    const float v1 = vd[idk * 3 + 1];
    const float v2 = vd[idk * 3 + 2];
    const float sv2 = v0 * v0 + v1 * v1 + v2 * v2;
    const float dt  = p0 * v0 + p1 * v1 + p2 * v2;
    const float ddx = (sp + sv2) - 2.0f * dt;       // reference formula
    d10[s] = ddx;
    dmn = fminf(dmn, ddx);
    dmx = fmaxf(dmx, ddx);
  }
  dmx = fmaxf(dmx, __shfl_xor(dmx, 32));
  dmn = fminf(dmn, __shfl_xor(dmn, 32));

  const float invmax = 1.0f / dmx;
  float wsum = 0.0f, pb0 = 0.0f, pb1 = 0.0f, pb2 = 0.0f;
  float rb[9];
#pragma unroll
  for (int a2i = 0; a2i < 9; ++a2i) rb[a2i] = 0.0f;

#pragma unroll
  for (int s = 0; s < 10; ++s) {
    const int idk = id10[s];
    const float u = 1.0f - d10[s] * invmax;
    const float w = u * u;
    wsum += w;
    const float* Rp = Rm + idk * 9;
    const float r00 = Rp[0], r01 = Rp[1], r02 = Rp[2];
    const float r10 = Rp[3], r11 = Rp[4], r12 = Rp[5];
    const float r20 = Rp[6], r21 = Rp[7], r22 = Rp[8];
    const float g0 = gv[idk * 3 + 0];
    const float g1 = gv[idk * 3 + 1];
    const float g2 = gv[idk * 3 + 2];
    const float t0 = tv[idk * 3 + 0];
    const float t1 = tv[idk * 3 + 1];
    const float t2 = tv[idk * 3 + 2];
    const float x0 = p0 - g0 - t0;
    const float x1 = p1 - g1 - t1;
    const float x2 = p2 - g2 - t2;
    pb0 += w * (r00 * x0 + r10 * x1 + r20 * x2 + g0);
    pb1 += w * (r01 * x0 + r11 * x1 + r21 * x2 + g1);
    pb2 += w * (r02 * x0 + r12 * x1 + r22 * x2 + g2);
    rb[0] += w * r00; rb[1] += w * r10; rb[2] += w * r20;
    rb[3] += w * r01; rb[4] += w * r11; rb[5] += w * r21;
    rb[6] += w * r02; rb[7] += w * r12; rb[8] += w * r22;
  }

  wsum += __shfl_xor(wsum, 32);
  pb0  += __shfl_xor(pb0, 32);
  pb1  += __shfl_xor(pb1, 32);
  pb2  += __shfl_xor(pb2, 32);
#pragma unroll
  for (int a2i = 0; a2i < 9; ++a2i) rb[a2i] += __shfl_xor(rb[a2i], 32);

  if (h == 0) {
    const float inw = 1.0f / wsum;
    float o0 = pb0 * inw;
    if (dmn > 0.00021f) o0 = 1000000000.0f;
    float* po = out + (size_t)gi * 3;
    po[0] = o0; po[1] = pb1 * inw; po[2] = pb2 * inw;
    float* ro = out + (size_t)NPTS * 3 + (size_t)gi * 9;
#pragma unroll
    for (int a2i = 0; a2i < 9; ++a2i) ro[a2i] = rb[a2i] * inw;
  }
}

// ---- fallback: R2-style scalar kernel (proven), if ws too small ----
__global__ __launch_bounds__(BT, 4) void dg_fb(
    const float* __restrict__ inp, const float* __restrict__ vd,
    const float* __restrict__ Rm, const float* __restrict__ gv,
    const float* __restrict__ tv, float* __restrict__ out)
{
  __shared__ uint32_t st[33 * BT];
  const int tid = threadIdx.x;
  const int q   = (tid >> 4) & 3;
  const int pl  = tid & 15;
  const int wv  = tid >> 6;
  const int gi  = blockIdx.x * 64 + wv * 16 + pl;
  const float p0 = inp[gi * 35 + 0];
  const float p1 = inp[gi * 35 + 1];
  const float p2 = inp[gi * 35 + 2];
  const float sp = p0 * p0 + p1 * p1 + p2 * p2;
  uint32_t m[KSEL];
#pragma unroll
  for (int k = 0; k < KSEL; ++k) m[k] = 0xFFFFFFFFu;
  int cnt = 0;
  float thr = __uint_as_float(0x7F7FFFFFu);
  const int jbase = q * (NNODES / 4);
  int lo = 0;
#pragma unroll
  for (int c = 0; c < 6; ++c) {
    const int hi = 32 << c;
    for (int i = lo; i < hi; ++i) {
      const int j = jbase + i;
      const float v0 = vd[j * 3 + 0], v1 = vd[j * 3 + 1], v2 = vd[j * 3 + 2];
      const float sv = v0 * v0 + v1 * v1 + v2 * v2;
      const float dt = p0 * v0 + p1 * v1 + p2 * v2;
      float d2 = fmaxf((sp + sv) - 2.0f * dt, 0.0f);
      if (d2 < thr) {
        st[cnt * BT + tid] = ((__float_as_uint(d2) & 0xFFFFF800u) << 1) | (uint32_t)j;
        if (++cnt == 33) {
          for (int u = 0; u < cnt; ++u) {
            const uint32_t x = st[u * BT + tid];
            if (x < m[KSEL - 1]) insert20(m, x);
          }
          cnt = 0; thr = thr_from(m[KSEL - 1]);
        }
      }
    }
    for (int u = 0; u < cnt; ++u) {
      const uint32_t x = st[u * BT + tid];
      if (x < m[KSEL - 1]) insert20(m, x);
    }
    cnt = 0; thr = thr_from(m[KSEL - 1]); lo = hi;
  }
  uint32_t arr[32];
#pragma unroll
  for (int k = 0; k < KSEL; ++k) arr[k] = m[k];
#pragma unroll
  for (int k = KSEL; k < 32; ++k) arr[k] = 0xFFFFFFFFu;
#pragma unroll
  for (int mask = 32; mask >= 16; mask >>= 1) {
#pragma unroll
    for (int k = 0; k < 16; ++k) {
      const uint32_t sa = (uint32_t)__shfl_xor((int)arr[k],      mask);
      const uint32_t sb = (uint32_t)__shfl_xor((int)arr[31 - k], mask);
      arr[k]      = umin32(arr[k],      sb);
      arr[31 - k] = umin32(arr[31 - k], sa);
    }
#pragma unroll
    for (int dd = 16; dd >= 1; dd >>= 1)
#pragma unroll
      for (int k = 0; k < 32; ++k)
        if ((k & dd) == 0) cmpswap(arr[k], arr[k | dd]);
  }
  int id5[5]; float d5[5];
  float dmn = 1e30f, dmx = -1e30f;
#pragma unroll
  for (int s = 0; s < 5; ++s) {
    const int idk = (int)(arr[4 * s + q] & 0xFFFu);
    id5[s] = idk;
    const float v0 = vd[idk * 3 + 0], v1 = vd[idk * 3 + 1], v2 = vd[idk * 3 + 2];
    const float sv = v0 * v0 + v1 * v1 + v2 * v2;
    const float dt = p0 * v0 + p1 * v1 + p2 * v2;
    const float ddx = (sp + sv) - 2.0f * dt;
    d5[s] = ddx; dmn = fminf(dmn, ddx); dmx = fmaxf(dmx, ddx);
  }
#pragma unroll
  for (int r = 16; r <= 32; r <<= 1) {
    dmx = fmaxf(dmx, __shfl_xor(dmx, r));
    dmn = fminf(dmn, __shfl_xor(dmn, r));
  }
  const float invmax = 1.0f / dmx;
  float wsum = 0.0f, pb0 = 0.0f, pb1 = 0.0f, pb2 = 0.0f;
  float rb[9];
#pragma unroll
  for (int a2i = 0; a2i < 9; ++a2i) rb[a2i] = 0.0f;
#pragma unroll
  for (int s = 0; s < 5; ++s) {
    const int idk = id5[s];
    const float u = 1.0f - d5[s] * invmax;
    const float w = u * u;
    wsum += w;
    const float* Rp = Rm + idk * 9;
    const float r00 = Rp[0], r01 = Rp[1], r02 = Rp[2];
    const float r10 = Rp[3], r11 = Rp[4], r12 = Rp[5];
    const float r20 = Rp[6], r21 = Rp[7], r22 = Rp[8];
    const float g0 = gv[idk * 3 + 0], g1 = gv[idk * 3 + 1], g2 = gv[idk * 3 + 2];
    const float t0 = tv[idk * 3 + 0], t1 = tv[idk * 3 + 1], t2 = tv[idk * 3 + 2];
    const float x0 = p0 - g0 - t0, x1 = p1 - g1 - t1, x2 = p2 - g2 - t2;
    pb0 += w * (r00 * x0 + r10 * x1 + r20 * x2 + g0);
    pb1 += w * (r01 * x0 + r11 * x1 + r21 * x2 + g1);
    pb2 += w * (r02 * x0 + r12 * x1 + r22 * x2 + g2);
    rb[0] += w * r00; rb[1] += w * r10; rb[2] += w * r20;
    rb[3] += w * r01; rb[4] += w * r11; rb[5] += w * r21;
    rb[6] += w * r02; rb[7] += w * r12; rb[8] += w * r22;
  }
#pragma unroll
  for (int r = 16; r <= 32; r <<= 1) {
    wsum += __shfl_xor(wsum, r);
    pb0 += __shfl_xor(pb0, r);
    pb1 += __shfl_xor(pb1, r);
    pb2 += __shfl_xor(pb2, r);
#pragma unroll
    for (int a2i = 0; a2i < 9; ++a2i) rb[a2i] += __shfl_xor(rb[a2i], r);
  }
  if (q == 0) {
    const float inw = 1.0f / wsum;
    float o0 = pb0 * inw;
    if (dmn > 0.00021f) o0 = 1000000000.0f;
    float* po = out + (size_t)gi * 3;
    po[0] = o0; po[1] = pb1 * inw; po[2] = pb2 * inw;
    float* ro = out + (size_t)NPTS * 3 + (size_t)gi * 9;
#pragma unroll
    for (int a2i = 0; a2i < 9; ++a2i) ro[a2i] = rb[a2i] * inw;
  }
}

extern "C" void kernel_launch(void* const* d_in, const int* in_sizes, int n_in,
                              void* d_out, int out_size, void* d_ws, size_t ws_size,
                              hipStream_t stream) {
  const float* inp = (const float*)d_in[0];
  const float* vd  = (const float*)d_in[1];
  const float* Rm  = (const float*)d_in[2];
  const float* gv  = (const float*)d_in[3];
  const float* tv  = (const float*)d_in[4];
  float* out = (float*)d_out;

  if (ws_size >= (size_t)WS_NEEDED) {
    unsigned short* aF = (unsigned short*)d_ws;
    float* svt = (float*)((char*)d_ws + AFRAG_BYTES);
    dg_prep<<<NNODES / 256, 256, 0, stream>>>(vd, aF, svt);
    dg_mfma<<<NPTS / 64, BT, 0, stream>>>(inp, vd, Rm, gv, tv,
                                          (const short8*)aF,
                                          (const float4*)svt, out);
  } else {
    dg_fb<<<NPTS / 64, BT, 0, stream>>>(inp, vd, Rm, gv, tv, out);
  }
}